// Round 19
// baseline (224.598 us; speedup 1.0000x reference)
//
#include <hip/hip_runtime.h>

#define NN 1024
#define FF 64
#define CC 4
#define EE 32768
#define HH 256

// ---- workspace layout (units of 4-byte words) ----
// zeroed region (one small memset): cnt + mask. adense zeroed by k_count on
// first iteration only (self-cleaned by k_edge_mlp afterwards).
#define OFF_ADENSE 0u         // 4194304 f  (N*N*C)
#define OFF_CNT    4194304u   // 4096 i
#define OFF_MASK   4198400u   // 32768 u32 (1 bit per (i,j) pair)
// ---- end of zero region: 4231168 words
#define OFF_OFFS   4231168u   // 4097 i
#define OFF_CURSOR 4235268u   // 4096 i
#define OFF_SRTS   4239364u   // 131072 i
#define OFF_SRTW   4370436u   // 131072 f
#define OFF_P      4501508u   // 262144 f
#define OFF_Q      4763652u   // 262144 f
#define OFF_QT     5025796u   // 262144 f  (Q transposed-packed: QTP[hq][j] float4)
// end 5287940 words = 21.2 MB

// ---------------------------------------------------------------------------
// S1: bucket counts per (c, dst) + conditional adense zeroing.
// Skip test: offs[4096] == C*E proves the previous iteration's full pipeline
// (including k_edge_mlp's read-and-zero self-clean of adense) completed on
// this workspace. Fresh/poisoned workspace fails the test -> full zero path.
__global__ __launch_bounds__(256)
void k_count(const int* __restrict__ ei, int* __restrict__ cnt,
             float4* __restrict__ adense4, const int* __restrict__ offs)
{
    unsigned t = blockIdx.x * 256u + threadIdx.x;   // t < C*E = 131072
    unsigned e = t & (EE - 1u);
    unsigned c = t >> 15;
    int dst = ei[c * 2 * EE + EE + e];
    atomicAdd(&cnt[c * NN + dst], 1);

    if (offs[4096] != CC * EE) {
        const unsigned base = blockIdx.x * 2048u + threadIdx.x;
        const float4 z = make_float4(0.f, 0.f, 0.f, 0.f);
#pragma unroll
        for (int u = 0; u < 8; ++u)
            adense4[base + u * 256u] = z;
    }
}

// S2: exclusive prefix sum over 4096 counts.
__global__ __launch_bounds__(256)
void k_scan(const int* __restrict__ cnt, int* __restrict__ offs, int* __restrict__ cursor)
{
    __shared__ int wsum[4];
    const int t = threadIdx.x;
    int c[16];
    int s = 0;
    const int4* cp = (const int4*)(cnt + t * 16);
#pragma unroll
    for (int u = 0; u < 4; ++u) {
        int4 v = cp[u];
        c[u * 4 + 0] = v.x; c[u * 4 + 1] = v.y; c[u * 4 + 2] = v.z; c[u * 4 + 3] = v.w;
        s += v.x + v.y + v.z + v.w;
    }
    int incl = s;
#pragma unroll
    for (int d = 1; d < 64; d <<= 1) {
        int v = __shfl_up(incl, d, 64);
        if ((t & 63) >= d) incl += v;
    }
    const int w = t >> 6;
    if ((t & 63) == 63) wsum[w] = incl;
    __syncthreads();
    int base = incl - s;                    // exclusive within wave
    for (int ww = 0; ww < w; ++ww) base += wsum[ww];
    int run = base;
#pragma unroll
    for (int u = 0; u < 16; ++u) {
        offs[t * 16 + u] = run;
        cursor[t * 16 + u] = run;
        run += c[u];
    }
    if (t == 255) offs[4096] = run;        // == C*E, also the self-clean flag
}

// S3: bucket-scatter edges + dense adjacency atomics + 1-bit pair mask.
__global__ __launch_bounds__(256)
void k_bucket_adj(const int* __restrict__ ei, const float* __restrict__ ew,
                  int* __restrict__ cursor, int* __restrict__ srt_src,
                  float* __restrict__ srt_w, float* __restrict__ adense,
                  unsigned* __restrict__ mask)
{
    unsigned t = blockIdx.x * 256u + threadIdx.x;
    unsigned e = t & (EE - 1u);
    unsigned c = t >> 15;
    int src = ei[c * 2 * EE + e];
    int dst = ei[c * 2 * EE + EE + e];
    float w = ew[c * EE + e];
    int pos = atomicAdd(&cursor[c * NN + dst], 1);
    srt_src[pos] = src;
    srt_w[pos] = w;
    unsigned pair = (unsigned)src * NN + (unsigned)dst;
    atomicAdd(&adense[(size_t)pair * CC + c], w);
    atomicOr(&mask[pair >> 5], 1u << (pair & 31u));
}

// ---------------------------------------------------------------------------
// Fused node pipeline — 1 node per 256-thread block, grid 1024 (r19 change:
// was 4 nodes x 1024 threads = 1 block/CU, so each __syncthreads stalled all
// 16 waves on the CU and the serial gather had no independent work to hide
// under; now 4 independent blocks/CU, barriers span only 4 waves).
// P/Q projection also writes transposed-packed QTP (r17, deleted k_qt).
__global__ __launch_bounds__(256)
void k_node(const float* __restrict__ x, const int* __restrict__ offs,
            const int* __restrict__ srt_src, const float* __restrict__ srt_w,
            const float* __restrict__ Wn1, const float* __restrict__ bn1,
            const float* __restrict__ Wn2, const float* __restrict__ bn2,
            const float* __restrict__ We1, const float* __restrict__ be1,
            const float* __restrict__ epsp,
            float* __restrict__ P, float* __restrict__ Q,
            float* __restrict__ QT)
{
    __shared__ float hval[256];
    __shared__ float hidl[256];
    __shared__ float part[4][64];
    __shared__ float xnl[64];
    const int tid = threadIdx.x;
    const int n = blockIdx.x;

    // gather: wave c handles bucket (c, n), lane = f
    {
        const int c = tid >> 6, lane = tid & 63;
        const int g = c * NN + n;
        const int beg = offs[g], end = offs[g + 1];
        float acc = 0.f;
        for (int k = beg; k < end; ++k)
            acc += x[srt_src[k] * FF + lane] * srt_w[k];
        const float ope = 1.0f + epsp[0];
        hval[c * 64 + lane] = acc + ope * x[n * FF + lane];
    }
    __syncthreads();

    // mlp1: hid[h] = relu(bn1[h] + sum_k hval[k] * Wn1[k][h])
    {
        const int h = tid;
        float acc = bn1[h];
#pragma unroll 8
        for (int k = 0; k < 256; ++k)
            acc += hval[k] * Wn1[k * 256 + h];
        hidl[h] = fmaxf(acc, 0.f);
    }
    __syncthreads();

    // mlp2 partials over 4 k-quarters
    {
        const int kq = tid >> 6, f = tid & 63;
        float p = 0.f;
#pragma unroll 8
        for (int k = kq * 64; k < kq * 64 + 64; ++k)
            p += hidl[k] * Wn2[k * 64 + f];
        part[kq][f] = p;
    }
    __syncthreads();
    if (tid < 64)
        xnl[tid] = bn2[tid] + part[0][tid] + part[1][tid]
                            + part[2][tid] + part[3][tid];
    __syncthreads();

    // P/Q projection (+ transposed-packed QT copy)
    {
        const int h = tid;
        float p = be1[h], q = 0.f;
#pragma unroll 8
        for (int f = 0; f < 64; ++f) {
            float xv = xnl[f];
            p += xv * We1[(4 + f) * 256 + h];
            q += xv * We1[(68 + f) * 256 + h];
        }
        P[n * 256 + h] = p;
        Q[n * 256 + h] = q;
        QT[((unsigned)(h >> 2) * NN + (unsigned)n) * 4u + (h & 3)] = q;
    }
}

// ---------------------------------------------------------------------------
// Edge MLP — exact r18 structure (82.5us verified, spill-clean) plus the
// adense SELF-CLEAN: the fix phase zeroes each adense entry after reading it
// (lane 0, one float4 store per listed pair ~ 2MB scattered), which lets
// k_count skip the 16.8MB re-zero on every iteration after the first.
// 2 i-rows per thread at grid 2048 (full wave slots); P/We2 scalar pipe,
// Q one coalesced VMEM b128 from QTP. launch_bounds (256,4) — (256,8)
// spills (r12 lesson).
__global__ __launch_bounds__(256, 4)
void k_edge_mlp(const float* __restrict__ P, const float* __restrict__ Q,
                const float4* __restrict__ QTP, float* __restrict__ adense,
                const unsigned* __restrict__ mask, const float* __restrict__ We1,
                const float* __restrict__ We2, const float* __restrict__ be2,
                float* __restrict__ out)
{
    __shared__ float4 delta[512];   // 8 KB fix-phase results
    __shared__ int nzlist[512];     // 2 KB
    __shared__ int lcnt;

    const int tid = threadIdx.x;
    const int w = tid >> 6, lane = tid & 63;
    const int iBase = blockIdx.y * 8, jBase = blockIdx.x * 64;
    const int j = jBase + lane;
    const int i0 = __builtin_amdgcn_readfirstlane(iBase + w * 2);  // wave-uniform

    if (tid == 0) lcnt = 0;
    __syncthreads();

    // nonzero detection for the thread's 2 rows from the 1-bit mask
    unsigned nzbits = 0;
#pragma unroll
    for (int ii = 0; ii < 2; ++ii) {
        const unsigned mw = mask[(unsigned)(i0 + ii) * 32u + ((unsigned)j >> 5)];
        if ((mw >> (j & 31)) & 1u) {
            nzbits |= 1u << ii;
            int idx = atomicAdd(&lcnt, 1);
            nzlist[idx] = (w * 2 + ii) * 64 + lane;
        }
    }
    __syncthreads();   // list complete

    const float4* P4  = (const float4*)P;    // P4[i*64 + hq]
    const float4* W24 = (const float4*)We2;  // W24[h] = We2[h][0..3]

    // ---- dense pass: 2 rows share each qv ----
    float4 acc0 = make_float4(0.f, 0.f, 0.f, 0.f);
    float4 acc1 = make_float4(0.f, 0.f, 0.f, 0.f);
    for (int hq = 0; hq < 64; ++hq) {
        const float4 qv  = QTP[hq * NN + j];             // coalesced VMEM b128
        const float4 pv0 = P4[(size_t)i0 * 64 + hq];     // scalar pipe
        const float4 pv1 = P4[(size_t)(i0 + 1) * 64 + hq];
        const float4 w20 = W24[hq * 4 + 0];
        const float4 w21 = W24[hq * 4 + 1];
        const float4 w22 = W24[hq * 4 + 2];
        const float4 w23 = W24[hq * 4 + 3];
        {
            const float v0 = fmaxf(pv0.x + qv.x, 0.f);
            const float v1 = fmaxf(pv0.y + qv.y, 0.f);
            const float v2 = fmaxf(pv0.z + qv.z, 0.f);
            const float v3 = fmaxf(pv0.w + qv.w, 0.f);
            acc0.x += v0 * w20.x + v1 * w21.x + v2 * w22.x + v3 * w23.x;
            acc0.y += v0 * w20.y + v1 * w21.y + v2 * w22.y + v3 * w23.y;
            acc0.z += v0 * w20.z + v1 * w21.z + v2 * w22.z + v3 * w23.z;
            acc0.w += v0 * w20.w + v1 * w21.w + v2 * w22.w + v3 * w23.w;
        }
        {
            const float v0 = fmaxf(pv1.x + qv.x, 0.f);
            const float v1 = fmaxf(pv1.y + qv.y, 0.f);
            const float v2 = fmaxf(pv1.z + qv.z, 0.f);
            const float v3 = fmaxf(pv1.w + qv.w, 0.f);
            acc1.x += v0 * w20.x + v1 * w21.x + v2 * w22.x + v3 * w23.x;
            acc1.y += v0 * w20.y + v1 * w21.y + v2 * w22.y + v3 * w23.y;
            acc1.z += v0 * w20.z + v1 * w21.z + v2 * w22.z + v3 * w23.z;
            acc1.w += v0 * w20.w + v1 * w21.w + v2 * w22.w + v3 * w23.w;
        }
    }

    // ---- fix phase (r13-proven) + adense self-clean ----
    {
        const int nfix = lcnt;
        for (int pi = w; pi < nfix; pi += 4) {
            const int lij = nzlist[pi];
            const int gi = iBase + (lij >> 6), gj = jBase + (lij & 63);
            float* ap = adense + ((size_t)gi * NN + gj) * 4;
            const float4 a = *(const float4*)ap;
            float o0 = 0.f, o1 = 0.f, o2 = 0.f, o3 = 0.f;
#pragma unroll
            for (int u = 0; u < 4; ++u) {
                const int h = u * 64 + lane;
                float s = a.x * We1[0 * 256 + h] + a.y * We1[1 * 256 + h]
                        + a.z * We1[2 * 256 + h] + a.w * We1[3 * 256 + h];
                float v = fmaxf(P[gi * 256 + h] + Q[gj * 256 + h] + s, 0.f);
                const float4 w2 = W24[h];
                o0 += v * w2.x; o1 += v * w2.y; o2 += v * w2.z; o3 += v * w2.w;
            }
#pragma unroll
            for (int d = 32; d > 0; d >>= 1) {
                o0 += __shfl_down(o0, d, 64);
                o1 += __shfl_down(o1, d, 64);
                o2 += __shfl_down(o2, d, 64);
                o3 += __shfl_down(o3, d, 64);
            }
            if (lane == 0) {
                delta[lij] = make_float4(o0, o1, o2, o3);
                *(float4*)ap = make_float4(0.f, 0.f, 0.f, 0.f);  // self-clean
            }
        }
    }
    __syncthreads();

    // ---- merge + store: 2 rows, each 1KB contiguous per wave ----
    const float4 b2 = *(const float4*)be2;
#pragma unroll
    for (int ii = 0; ii < 2; ++ii) {
        const int lij = (w * 2 + ii) * 64 + lane;
        const float4 dfx = delta[lij];
        const float4 av = ii ? acc1 : acc0;
        const bool nzf = (nzbits >> ii) & 1u;
        float4 o;
        o.x = (nzf ? dfx.x : av.x) + b2.x;
        o.y = (nzf ? dfx.y : av.y) + b2.y;
        o.z = (nzf ? dfx.z : av.z) + b2.z;
        o.w = (nzf ? dfx.w : av.w) + b2.w;
        *(float4*)(out + ((size_t)(i0 + ii) * NN + j) * 4) = o;
    }
}

// ---------------------------------------------------------------------------
extern "C" void kernel_launch(void* const* d_in, const int* in_sizes, int n_in,
                              void* d_out, int out_size, void* d_ws, size_t ws_size,
                              hipStream_t stream)
{
    (void)in_sizes; (void)n_in; (void)out_size; (void)ws_size;
    const float* x   = (const float*)d_in[0];
    const int*   ei  = (const int*)d_in[1];
    const float* ew  = (const float*)d_in[2];
    const float* Wn1 = (const float*)d_in[3];
    const float* bn1 = (const float*)d_in[4];
    const float* Wn2 = (const float*)d_in[5];
    const float* bn2 = (const float*)d_in[6];
    const float* We1 = (const float*)d_in[7];
    const float* be1 = (const float*)d_in[8];
    const float* We2 = (const float*)d_in[9];
    const float* be2 = (const float*)d_in[10];
    const float* eps = (const float*)d_in[11];
    float* out = (float*)d_out;

    float*    ws     = (float*)d_ws;
    float*    adense = ws + OFF_ADENSE;
    int*      cnt    = (int*)(ws + OFF_CNT);
    unsigned* mask   = (unsigned*)(ws + OFF_MASK);
    int*      offs   = (int*)(ws + OFF_OFFS);
    int*      cursor = (int*)(ws + OFF_CURSOR);
    int*      srts   = (int*)(ws + OFF_SRTS);
    float*    srtw   = ws + OFF_SRTW;
    float*    Pb     = ws + OFF_P;
    float*    Qb     = ws + OFF_Q;
    float*    QTb    = ws + OFF_QT;

    // zero cnt + mask only (adense zeroed conditionally inside k_count)
    (void)hipMemsetAsync((void*)cnt, 0, (size_t)(4096 + 32768) * sizeof(int), stream);

    k_count     <<<(CC * EE) / 256, 256, 0, stream>>>(ei, cnt, (float4*)adense, offs);
    k_scan      <<<1, 256, 0, stream>>>(cnt, offs, cursor);
    k_bucket_adj<<<(CC * EE) / 256, 256, 0, stream>>>(ei, ew, cursor, srts, srtw,
                                                      adense, mask);
    k_node      <<<NN, 256, 0, stream>>>(x, offs, srts, srtw,
                                         Wn1, bn1, Wn2, bn2, We1, be1, eps,
                                         Pb, Qb, QTb);

    dim3 g(NN / 64, NN / 8);
    k_edge_mlp<<<g, 256, 0, stream>>>(Pb, Qb, (const float4*)QTb, adense, mask,
                                      We1, We2, be2, out);
}

// Round 20
// 220.508 us; speedup vs baseline: 1.0185x; 1.0185x over previous
//
#include <hip/hip_runtime.h>

#define NN 1024
#define FF 64
#define CC 4
#define EE 32768
#define HH 256

// ---- workspace layout (units of 4-byte words) ----
// zeroed region (one small memset): cnt + mask. adense zeroed by k_count.
#define OFF_ADENSE 0u         // 4194304 f  (N*N*C)
#define OFF_CNT    4194304u   // 4096 i
#define OFF_MASK   4198400u   // 32768 u32 (1 bit per (i,j) pair)
// ---- end of zero region: 4231168 words
#define OFF_OFFS   4231168u   // 4097 i
#define OFF_CURSOR 4235268u   // 4096 i
#define OFF_SRTS   4239364u   // 131072 i
#define OFF_SRTW   4370436u   // 131072 f
#define OFF_P      4501508u   // 262144 f
#define OFF_Q      4763652u   // 262144 f
#define OFF_QT     5025796u   // 262144 f  (Q transposed-packed: QTP[hq][j] float4)
// end 5287940 words = 21.2 MB

// ---------------------------------------------------------------------------
// S1: bucket counts per (c, dst) + zero adense (lane-consecutive full-line
// float4 stores, verified safe rounds 0-18).
__global__ __launch_bounds__(256)
void k_count(const int* __restrict__ ei, int* __restrict__ cnt,
             float4* __restrict__ adense4)
{
    unsigned t = blockIdx.x * 256u + threadIdx.x;   // t < C*E = 131072
    unsigned e = t & (EE - 1u);
    unsigned c = t >> 15;
    int dst = ei[c * 2 * EE + EE + e];
    atomicAdd(&cnt[c * NN + dst], 1);

    const unsigned base = blockIdx.x * 2048u + threadIdx.x;
    const float4 z = make_float4(0.f, 0.f, 0.f, 0.f);
#pragma unroll
    for (int u = 0; u < 8; ++u)
        adense4[base + u * 256u] = z;
}

// S2: exclusive prefix sum over 4096 counts.
__global__ __launch_bounds__(256)
void k_scan(const int* __restrict__ cnt, int* __restrict__ offs, int* __restrict__ cursor)
{
    __shared__ int wsum[4];
    const int t = threadIdx.x;
    int c[16];
    int s = 0;
    const int4* cp = (const int4*)(cnt + t * 16);
#pragma unroll
    for (int u = 0; u < 4; ++u) {
        int4 v = cp[u];
        c[u * 4 + 0] = v.x; c[u * 4 + 1] = v.y; c[u * 4 + 2] = v.z; c[u * 4 + 3] = v.w;
        s += v.x + v.y + v.z + v.w;
    }
    int incl = s;
#pragma unroll
    for (int d = 1; d < 64; d <<= 1) {
        int v = __shfl_up(incl, d, 64);
        if ((t & 63) >= d) incl += v;
    }
    const int w = t >> 6;
    if ((t & 63) == 63) wsum[w] = incl;
    __syncthreads();
    int base = incl - s;                    // exclusive within wave
    for (int ww = 0; ww < w; ++ww) base += wsum[ww];
    int run = base;
#pragma unroll
    for (int u = 0; u < 16; ++u) {
        offs[t * 16 + u] = run;
        cursor[t * 16 + u] = run;
        run += c[u];
    }
    if (t == 255) offs[4096] = run;
}

// S3: bucket-scatter edges + dense adjacency atomics + 1-bit pair mask.
__global__ __launch_bounds__(256)
void k_bucket_adj(const int* __restrict__ ei, const float* __restrict__ ew,
                  int* __restrict__ cursor, int* __restrict__ srt_src,
                  float* __restrict__ srt_w, float* __restrict__ adense,
                  unsigned* __restrict__ mask)
{
    unsigned t = blockIdx.x * 256u + threadIdx.x;
    unsigned e = t & (EE - 1u);
    unsigned c = t >> 15;
    int src = ei[c * 2 * EE + e];
    int dst = ei[c * 2 * EE + EE + e];
    float w = ew[c * EE + e];
    int pos = atomicAdd(&cursor[c * NN + dst], 1);
    srt_src[pos] = src;
    srt_w[pos] = w;
    unsigned pair = (unsigned)src * NN + (unsigned)dst;
    atomicAdd(&adense[(size_t)pair * CC + c], w);
    atomicOr(&mask[pair >> 5], 1u << (pair & 31u));
}

// ---------------------------------------------------------------------------
// Fused node pipeline; P/Q projection also writes transposed-packed QTP
// (r17-verified, deleted the separate k_qt dispatch).
__global__ __launch_bounds__(1024)
void k_node(const float* __restrict__ x, const int* __restrict__ offs,
            const int* __restrict__ srt_src, const float* __restrict__ srt_w,
            const float* __restrict__ Wn1, const float* __restrict__ bn1,
            const float* __restrict__ Wn2, const float* __restrict__ bn2,
            const float* __restrict__ We1, const float* __restrict__ be1,
            const float* __restrict__ epsp,
            float* __restrict__ P, float* __restrict__ Q,
            float* __restrict__ QT)
{
    __shared__ float hval[4][256];
    __shared__ float hidl[4][256];
    __shared__ float part[4][4][64];
    __shared__ float xnl[4][64];
    const int tid = threadIdx.x;
    const int n0 = blockIdx.x * 4;

    {
        const int w = tid >> 6, lane = tid & 63;
        const int c = w & 3, nn = w >> 2;
        const int g = c * NN + (n0 + nn);
        const int beg = offs[g], end = offs[g + 1];
        float acc = 0.f;
        for (int k = beg; k < end; ++k)
            acc += x[srt_src[k] * FF + lane] * srt_w[k];
        const float ope = 1.0f + epsp[0];
        hval[nn][c * 64 + lane] = acc + ope * x[(n0 + nn) * FF + lane];
    }
    __syncthreads();

    {
        const int nn = tid >> 8, h = tid & 255;
        float acc = bn1[h];
#pragma unroll 8
        for (int k = 0; k < 256; ++k)
            acc += hval[nn][k] * Wn1[k * 256 + h];
        hidl[nn][h] = fmaxf(acc, 0.f);
    }
    __syncthreads();

    {
        const int kq = tid >> 8, nn = (tid >> 6) & 3, f = tid & 63;
        float p = 0.f;
#pragma unroll 8
        for (int k = kq * 64; k < kq * 64 + 64; ++k)
            p += hidl[nn][k] * Wn2[k * 64 + f];
        part[kq][nn][f] = p;
    }
    __syncthreads();
    if (tid < 256) {
        const int nn = tid >> 6, f = tid & 63;
        xnl[nn][f] = bn2[f] + part[0][nn][f] + part[1][nn][f]
                             + part[2][nn][f] + part[3][nn][f];
    }
    __syncthreads();

    {
        const int r = tid >> 8, h = tid & 255;
        float p = be1[h], q = 0.f;
#pragma unroll 8
        for (int f = 0; f < 64; ++f) {
            float xv = xnl[r][f];
            p += xv * We1[(4 + f) * 256 + h];
            q += xv * We1[(68 + f) * 256 + h];
        }
        P[(n0 + r) * 256 + h] = p;
        Q[(n0 + r) * 256 + h] = q;
        // transposed-packed copy: QTP4[(h>>2)*NN + n].comp(h&3) = q
        QT[((unsigned)(h >> 2) * NN + (unsigned)(n0 + r)) * 4u + (h & 3)] = q;
    }
}

// ---------------------------------------------------------------------------
// Edge MLP — r13 structure with 2 i-rows PER THREAD at grid 2048 (r18,
// verified best: 82.5us, spill-clean 16.4MB WRITE, VALUBusy 63%).
// r19's adense self-clean cost +1.7us (scattered stores, +4 VGPR) and is
// reverted. Dense loop: P/We2 scalar pipe, Q one coalesced VMEM b128 from
// QTP; 2 rows share each qv (halves L1 traffic at FULL 32 wave slots —
// r16's 4-row variant failed only because grid 1024 halved wave slots).
// Fix phase + stores: verified r13 form. launch_bounds (256,4) — (256,8)
// caps VGPR at 64 and spills (r12 lesson).
__global__ __launch_bounds__(256, 4)
void k_edge_mlp(const float* __restrict__ P, const float* __restrict__ Q,
                const float4* __restrict__ QTP, const float* __restrict__ adense,
                const unsigned* __restrict__ mask, const float* __restrict__ We1,
                const float* __restrict__ We2, const float* __restrict__ be2,
                float* __restrict__ out)
{
    __shared__ float4 delta[512];   // 8 KB fix-phase results
    __shared__ int nzlist[512];     // 2 KB
    __shared__ int lcnt;

    const int tid = threadIdx.x;
    const int w = tid >> 6, lane = tid & 63;
    const int iBase = blockIdx.y * 8, jBase = blockIdx.x * 64;
    const int j = jBase + lane;
    const int i0 = __builtin_amdgcn_readfirstlane(iBase + w * 2);  // wave-uniform

    if (tid == 0) lcnt = 0;
    __syncthreads();

    // nonzero detection for the thread's 2 rows from the 1-bit mask
    unsigned nzbits = 0;
#pragma unroll
    for (int ii = 0; ii < 2; ++ii) {
        const unsigned mw = mask[(unsigned)(i0 + ii) * 32u + ((unsigned)j >> 5)];
        if ((mw >> (j & 31)) & 1u) {
            nzbits |= 1u << ii;
            int idx = atomicAdd(&lcnt, 1);
            nzlist[idx] = (w * 2 + ii) * 64 + lane;
        }
    }
    __syncthreads();   // list complete

    const float4* P4  = (const float4*)P;    // P4[i*64 + hq]
    const float4* W24 = (const float4*)We2;  // W24[h] = We2[h][0..3]

    // ---- dense pass: 2 rows share each qv ----
    float4 acc0 = make_float4(0.f, 0.f, 0.f, 0.f);
    float4 acc1 = make_float4(0.f, 0.f, 0.f, 0.f);
    for (int hq = 0; hq < 64; ++hq) {
        const float4 qv  = QTP[hq * NN + j];             // coalesced VMEM b128
        const float4 pv0 = P4[(size_t)i0 * 64 + hq];     // scalar pipe
        const float4 pv1 = P4[(size_t)(i0 + 1) * 64 + hq];
        const float4 w20 = W24[hq * 4 + 0];
        const float4 w21 = W24[hq * 4 + 1];
        const float4 w22 = W24[hq * 4 + 2];
        const float4 w23 = W24[hq * 4 + 3];
        {
            const float v0 = fmaxf(pv0.x + qv.x, 0.f);
            const float v1 = fmaxf(pv0.y + qv.y, 0.f);
            const float v2 = fmaxf(pv0.z + qv.z, 0.f);
            const float v3 = fmaxf(pv0.w + qv.w, 0.f);
            acc0.x += v0 * w20.x + v1 * w21.x + v2 * w22.x + v3 * w23.x;
            acc0.y += v0 * w20.y + v1 * w21.y + v2 * w22.y + v3 * w23.y;
            acc0.z += v0 * w20.z + v1 * w21.z + v2 * w22.z + v3 * w23.z;
            acc0.w += v0 * w20.w + v1 * w21.w + v2 * w22.w + v3 * w23.w;
        }
        {
            const float v0 = fmaxf(pv1.x + qv.x, 0.f);
            const float v1 = fmaxf(pv1.y + qv.y, 0.f);
            const float v2 = fmaxf(pv1.z + qv.z, 0.f);
            const float v3 = fmaxf(pv1.w + qv.w, 0.f);
            acc1.x += v0 * w20.x + v1 * w21.x + v2 * w22.x + v3 * w23.x;
            acc1.y += v0 * w20.y + v1 * w21.y + v2 * w22.y + v3 * w23.y;
            acc1.z += v0 * w20.z + v1 * w21.z + v2 * w22.z + v3 * w23.z;
            acc1.w += v0 * w20.w + v1 * w21.w + v2 * w22.w + v3 * w23.w;
        }
    }

    // ---- fix phase (r13-proven): wave per listed pair, lane over h ----
    {
        const int nfix = lcnt;
        for (int pi = w; pi < nfix; pi += 4) {
            const int lij = nzlist[pi];
            const int gi = iBase + (lij >> 6), gj = jBase + (lij & 63);
            const float4 a = *(const float4*)(adense + ((size_t)gi * NN + gj) * 4);
            float o0 = 0.f, o1 = 0.f, o2 = 0.f, o3 = 0.f;
#pragma unroll
            for (int u = 0; u < 4; ++u) {
                const int h = u * 64 + lane;
                float s = a.x * We1[0 * 256 + h] + a.y * We1[1 * 256 + h]
                        + a.z * We1[2 * 256 + h] + a.w * We1[3 * 256 + h];
                float v = fmaxf(P[gi * 256 + h] + Q[gj * 256 + h] + s, 0.f);
                const float4 w2 = W24[h];
                o0 += v * w2.x; o1 += v * w2.y; o2 += v * w2.z; o3 += v * w2.w;
            }
#pragma unroll
            for (int d = 32; d > 0; d >>= 1) {
                o0 += __shfl_down(o0, d, 64);
                o1 += __shfl_down(o1, d, 64);
                o2 += __shfl_down(o2, d, 64);
                o3 += __shfl_down(o3, d, 64);
            }
            if (lane == 0)
                delta[lij] = make_float4(o0, o1, o2, o3);
        }
    }
    __syncthreads();

    // ---- merge + store: 2 rows, each 1KB contiguous per wave ----
    const float4 b2 = *(const float4*)be2;
#pragma unroll
    for (int ii = 0; ii < 2; ++ii) {
        const int lij = (w * 2 + ii) * 64 + lane;
        const float4 dfx = delta[lij];
        const float4 av = ii ? acc1 : acc0;
        const bool nzf = (nzbits >> ii) & 1u;
        float4 o;
        o.x = (nzf ? dfx.x : av.x) + b2.x;
        o.y = (nzf ? dfx.y : av.y) + b2.y;
        o.z = (nzf ? dfx.z : av.z) + b2.z;
        o.w = (nzf ? dfx.w : av.w) + b2.w;
        *(float4*)(out + ((size_t)(i0 + ii) * NN + j) * 4) = o;
    }
}

// ---------------------------------------------------------------------------
extern "C" void kernel_launch(void* const* d_in, const int* in_sizes, int n_in,
                              void* d_out, int out_size, void* d_ws, size_t ws_size,
                              hipStream_t stream)
{
    (void)in_sizes; (void)n_in; (void)out_size; (void)ws_size;
    const float* x   = (const float*)d_in[0];
    const int*   ei  = (const int*)d_in[1];
    const float* ew  = (const float*)d_in[2];
    const float* Wn1 = (const float*)d_in[3];
    const float* bn1 = (const float*)d_in[4];
    const float* Wn2 = (const float*)d_in[5];
    const float* bn2 = (const float*)d_in[6];
    const float* We1 = (const float*)d_in[7];
    const float* be1 = (const float*)d_in[8];
    const float* We2 = (const float*)d_in[9];
    const float* be2 = (const float*)d_in[10];
    const float* eps = (const float*)d_in[11];
    float* out = (float*)d_out;

    float*    ws     = (float*)d_ws;
    float*    adense = ws + OFF_ADENSE;
    int*      cnt    = (int*)(ws + OFF_CNT);
    unsigned* mask   = (unsigned*)(ws + OFF_MASK);
    int*      offs   = (int*)(ws + OFF_OFFS);
    int*      cursor = (int*)(ws + OFF_CURSOR);
    int*      srts   = (int*)(ws + OFF_SRTS);
    float*    srtw   = ws + OFF_SRTW;
    float*    Pb     = ws + OFF_P;
    float*    Qb     = ws + OFF_Q;
    float*    QTb    = ws + OFF_QT;

    // zero cnt + mask only (adense zeroed inside k_count)
    (void)hipMemsetAsync((void*)cnt, 0, (size_t)(4096 + 32768) * sizeof(int), stream);

    k_count     <<<(CC * EE) / 256, 256, 0, stream>>>(ei, cnt, (float4*)adense);
    k_scan      <<<1, 256, 0, stream>>>(cnt, offs, cursor);
    k_bucket_adj<<<(CC * EE) / 256, 256, 0, stream>>>(ei, ew, cursor, srts, srtw,
                                                      adense, mask);
    k_node      <<<NN / 4, 1024, 0, stream>>>(x, offs, srts, srtw,
                                              Wn1, bn1, Wn2, bn2, We1, be1, eps,
                                              Pb, Qb, QTb);

    dim3 g(NN / 64, NN / 8);
    k_edge_mlp<<<g, 256, 0, stream>>>(Pb, Qb, (const float4*)QTb, adense, mask,
                                      We1, We2, be2, out);
}